// Round 1
// baseline (3865.334 us; speedup 1.0000x reference)
//
#include <hip/hip_runtime.h>
#include <math.h>

// Problem constants (b=1 hard-coded)
#define H  24
#define NN 3072
#define D  128
#define G  16
#define BM 192
#define TOPK_K 896
#define PST 68             // P-tile LDS row stride (floats)
#define OUT2_OFF ((size_t)H * NN * D)
#define KV_HALF_BYTES ((size_t)H * NN * D * 2)   // 18874368
#define CSD_BYTES ((size_t)H * G * NN * 8)       // 9437184 (float64 cs)

// exp(s*scale) = exp2(s * scale * log2(e)); scale = 1/sqrt(128)
#define LOG2E_SCALE 0.12751743822f

typedef _Float16 half8 __attribute__((ext_vector_type(8)));
typedef _Float16 half4v __attribute__((ext_vector_type(4)));
typedef __fp16 fp16x2 __attribute__((ext_vector_type(2)));
typedef float floatx4 __attribute__((ext_vector_type(4)));

__device__ __forceinline__ floatx4 fzero4() {
  floatx4 z = {0.f, 0.f, 0.f, 0.f};
  return z;
}
// RTE pack (unbiased) — used for input fragments
__device__ __forceinline__ half8 pack_h8_rte(float4 a, float4 b) {
  half8 r;
  r[0] = (_Float16)a.x; r[1] = (_Float16)a.y; r[2] = (_Float16)a.z; r[3] = (_Float16)a.w;
  r[4] = (_Float16)b.x; r[5] = (_Float16)b.y; r[6] = (_Float16)b.z; r[7] = (_Float16)b.w;
  return r;
}
// RTZ packed cvt (1 instr per pair) — used for P (p>=0; small bias cancels in o - sp)
__device__ __forceinline__ half8 pack_h8_rtz(float4 a, float4 b) {
  fp16x2 h0 = __builtin_amdgcn_cvt_pkrtz(a.x, a.y);
  fp16x2 h1 = __builtin_amdgcn_cvt_pkrtz(a.z, a.w);
  fp16x2 h2 = __builtin_amdgcn_cvt_pkrtz(b.x, b.y);
  fp16x2 h3 = __builtin_amdgcn_cvt_pkrtz(b.z, b.w);
  half8 r;
  r[0] = (_Float16)h0[0]; r[1] = (_Float16)h0[1];
  r[2] = (_Float16)h1[0]; r[3] = (_Float16)h1[1];
  r[4] = (_Float16)h2[0]; r[5] = (_Float16)h2[1];
  r[6] = (_Float16)h3[0]; r[7] = (_Float16)h3[1];
  return r;
}
// residual: x - (float)f16(x)
__device__ __forceinline__ half8 pack_h8_residual(float4 a, float4 b, half8 hi) {
  float4 ra = make_float4(a.x - (float)hi[0], a.y - (float)hi[1],
                          a.z - (float)hi[2], a.w - (float)hi[3]);
  float4 rb = make_float4(b.x - (float)hi[4], b.y - (float)hi[5],
                          b.z - (float)hi[6], b.w - (float)hi[7]);
  return pack_h8_rte(ra, rb);
}

// ---------------- threefry2x32 (exact JAX semantics, validated round 1) ----------------
__device__ __forceinline__ void tf2x32(unsigned k0, unsigned k1, unsigned x0, unsigned x1,
                                       unsigned* o0, unsigned* o1) {
  unsigned ks2 = k0 ^ k1 ^ 0x1BD11BDAu;
  unsigned v0 = x0 + k0, v1 = x1 + k1;
#define TF_RND(r) { v0 += v1; v1 = (v1 << (r)) | (v1 >> (32 - (r))); v1 ^= v0; }
  TF_RND(13) TF_RND(15) TF_RND(26) TF_RND(6)   v0 += k1;  v1 += ks2 + 1u;
  TF_RND(17) TF_RND(29) TF_RND(16) TF_RND(24)  v0 += ks2; v1 += k0 + 2u;
  TF_RND(13) TF_RND(15) TF_RND(26) TF_RND(6)   v0 += k0;  v1 += k1 + 3u;
  TF_RND(17) TF_RND(29) TF_RND(16) TF_RND(24)  v0 += k1;  v1 += ks2 + 4u;
  TF_RND(13) TF_RND(15) TF_RND(26) TF_RND(6)   v0 += ks2; v1 += k0 + 5u;
#undef TF_RND
  *o0 = v0; *o1 = v1;
}

__global__ __launch_bounds__(256)
void rmask_kernel(float* __restrict__ mask) {
  const unsigned S = H * G * NN;
  unsigned i = blockIdx.x * 256u + threadIdx.x;
  if (i >= S) return;
  unsigned hb, lb, a, b;
  unsigned k1a, k1b, k2a, k2b;
  tf2x32(0u, 1u, 0u, 0u, &k1a, &k1b);
  tf2x32(0u, 1u, 0u, 1u, &k2a, &k2b);
  tf2x32(k1a, k1b, 0u, i, &a, &b); hb = a ^ b;
  tf2x32(k2a, k2b, 0u, i, &a, &b); lb = a ^ b;
  unsigned r = ((hb % 100u) * 96u + (lb % 100u)) % 100u;
  mask[i] = (r == 0u) ? 1.0f : 0.0f;
}

// ---------------- phase 0: k -> f16 hi + f16 residual (row-major) ----------------
__global__ __launch_bounds__(256)
void cvt_k_kernel(const float* __restrict__ k, _Float16* __restrict__ khi,
                  _Float16* __restrict__ klo) {
  size_t i = (size_t)blockIdx.x * 256 + threadIdx.x;   // 8 elems per thread
  const float4* src = (const float4*)k + i * 2;
  float4 a = src[0], b = src[1];
  half8 hi = pack_h8_rte(a, b);
  *(half8*)(khi + i * 8) = hi;
  *(half8*)(klo + i * 8) = pack_h8_residual(a, b, hi);
}

// ---------------- phase 0: v -> f16 transposed vT[h][d][key] ----------------
__global__ __launch_bounds__(256)
void cvt_vT_kernel(const float* __restrict__ v, _Float16* __restrict__ vT) {
  __shared__ _Float16 t[64][68];
  const int h = blockIdx.z, k0 = blockIdx.x * 64, d0 = blockIdx.y * 64;
  const int tid = threadIdx.x;
  const int c4 = tid & 15, r = tid >> 4;
#pragma unroll
  for (int i = 0; i < 4; ++i) {
    int row = r + i * 16;  // key row within tile
    float4 x = *(const float4*)(v + ((size_t)(h * NN + k0 + row)) * D + d0 + c4 * 4);
    t[c4 * 4 + 0][row] = (_Float16)x.x;
    t[c4 * 4 + 1][row] = (_Float16)x.y;
    t[c4 * 4 + 2][row] = (_Float16)x.z;
    t[c4 * 4 + 3][row] = (_Float16)x.w;
  }
  __syncthreads();
#pragma unroll
  for (int i = 0; i < 4; ++i) {
    int drow = r + i * 16;  // d within tile
    half4v val = *(const half4v*)&t[drow][c4 * 4];
    *(half4v*)(vT + (size_t)(h * D + d0 + drow) * NN + k0 + c4 * 4) = val;
  }
}

// ---------------- dense attention: fused 2-pass MFMA (split-f16 QK^T), o + f64 cs ----------------
// Restructured vs prior version:
//  * 16 query rows/wave (TQb=64) -> grid 1152 blocks, launch_bounds(256,3): 2x waves, ~3 blocks/CU
//  * K fragments double-buffered in registers: tile t+1's 8 half8 loads issue before tile t's MFMAs
//  * V fragments batched 8-at-a-time, issued before the exp/cs phase (latency hidden under VALU work)
//  * cs: f64 csp tree-reduced across l4 lane-groups via shfl_xor (deterministic), ONE atomic per
//    key per wave from lanes 0-15 (8x fewer same-address f64 atomics)
__global__ __launch_bounds__(256, 3)
void dense_kernel(const float* __restrict__ q, const _Float16* __restrict__ khi_g,
                  const _Float16* __restrict__ klo_g, const _Float16* __restrict__ vT,
                  float* __restrict__ out, double* __restrict__ csb) {
  __shared__ float p_sh[4 * 16 * PST];   // per-wave private 16-row stripes; NO barriers needed
  const int tid = threadIdx.x;
  const int wave = tid >> 6, lane = tid & 63;
  const int l15 = lane & 15, l4 = lane >> 4;
  const int h = blockIdx.y;
  const int rowbase = blockIdx.x * 64 + wave * 16;
  const _Float16* khi = khi_g + (size_t)h * NN * D;
  const _Float16* klo = klo_g + (size_t)h * NN * D;
  const _Float16* vh = vT + (size_t)h * D * NN;
  float* p_wave = p_sh + wave * 16 * PST;

  // Q A-fragments hi+lo, register-resident: A[m=l15][k=l4*8+j]
  half8 qh[4], ql[4];
#pragma unroll
  for (int ds = 0; ds < 4; ++ds) {
    const float* qp = q + ((size_t)(h * NN + rowbase + l15)) * D + ds * 32 + l4 * 8;
    float4 a = *(const float4*)qp, b = *(const float4*)(qp + 4);
    qh[ds] = pack_h8_rte(a, b);
    ql[ds] = pack_h8_residual(a, b, qh[ds]);
  }

  // K fragment register double-buffer. t indexes 16-key column tiles (0..191).
  // t==192 over-reads one tile past this head's khi/klo: lands in the next ws region
  // (klo / vT) -- harmless, values unused.
  half8 kbh[2][4], kbl[2][4];
#define LOADK2(bb, t) { const size_t ko_ = (size_t)((t) * 16 + l15) * D + l4 * 8;        \
  _Pragma("unroll") for (int ds_ = 0; ds_ < 4; ++ds_) {                                  \
    kbh[bb][ds_] = *(const half8*)(khi + ko_ + ds_ * 32);                                \
    kbl[bb][ds_] = *(const half8*)(klo + ko_ + ds_ * 32); } }

  // ---- pass 1: per-lane partial row sums (split-precision QK^T) ----
  float Lacc[4] = {0.f, 0.f, 0.f, 0.f};
  LOADK2(0, 0)
  for (int t4 = 0; t4 < 48; ++t4) {
    floatx4 S[4];
#pragma unroll
    for (int nt = 0; nt < 4; ++nt) S[nt] = fzero4();
#pragma unroll
    for (int nt = 0; nt < 4; ++nt) {
      const int b = nt & 1;
      LOADK2(b ^ 1, t4 * 4 + nt + 1)   // prefetch next 16-key tile while computing this one
#pragma unroll
      for (int ds = 0; ds < 4; ++ds) {
        S[nt] = __builtin_amdgcn_mfma_f32_16x16x32_f16(qh[ds], kbh[b][ds], S[nt], 0, 0, 0);
        S[nt] = __builtin_amdgcn_mfma_f32_16x16x32_f16(qh[ds], kbl[b][ds], S[nt], 0, 0, 0);
        S[nt] = __builtin_amdgcn_mfma_f32_16x16x32_f16(ql[ds], kbh[b][ds], S[nt], 0, 0, 0);
      }
    }
#pragma unroll
    for (int nt = 0; nt < 4; ++nt)
#pragma unroll
      for (int r = 0; r < 4; ++r)
        Lacc[r] += __builtin_amdgcn_exp2f(S[nt][r] * LOG2E_SCALE);
  }
  float invL[4];
#pragma unroll
  for (int r = 0; r < 4; ++r) {
    float x = Lacc[r];
    x += __shfl_xor(x, 1); x += __shfl_xor(x, 2);
    x += __shfl_xor(x, 4); x += __shfl_xor(x, 8);
    invL[r] = 1.0f / x;   // row = l4*4 + r  (matches C-layout)
  }

  // ---- pass 2: p, cs (f64, wave-reduced atomics), PV ----
  const int gg0 = rowbase / BM;
  double* csrow = csb + ((size_t)h * G + gg0) * NN;
  floatx4 O[8];
#pragma unroll
  for (int dt = 0; dt < 8; ++dt) O[dt] = fzero4();

  LOADK2(0, 0)
  for (int t4 = 0; t4 < 48; ++t4) {
    const int kc = t4 * 64;
    floatx4 S[4];
#pragma unroll
    for (int nt = 0; nt < 4; ++nt) S[nt] = fzero4();
#pragma unroll
    for (int nt = 0; nt < 4; ++nt) {
      const int b = nt & 1;
      LOADK2(b ^ 1, t4 * 4 + nt + 1)
#pragma unroll
      for (int ds = 0; ds < 4; ++ds) {
        S[nt] = __builtin_amdgcn_mfma_f32_16x16x32_f16(qh[ds], kbh[b][ds], S[nt], 0, 0, 0);
        S[nt] = __builtin_amdgcn_mfma_f32_16x16x32_f16(qh[ds], kbl[b][ds], S[nt], 0, 0, 0);
        S[nt] = __builtin_amdgcn_mfma_f32_16x16x32_f16(ql[ds], kbh[b][ds], S[nt], 0, 0, 0);
      }
    }
    // batch V fragments for ks=0 now; their latency hides under the exp/cs VALU phase
    half8 vb[8];
#pragma unroll
    for (int dt = 0; dt < 8; ++dt)
      vb[dt] = *(const half8*)(vh + (size_t)(dt * 16 + l15) * NN + kc + l4 * 8);
    // exp, cs partial (f64), LDS P stripe
#pragma unroll
    for (int nt = 0; nt < 4; ++nt) {
      float e0 = __builtin_amdgcn_exp2f(S[nt][0] * LOG2E_SCALE);
      float e1 = __builtin_amdgcn_exp2f(S[nt][1] * LOG2E_SCALE);
      float e2 = __builtin_amdgcn_exp2f(S[nt][2] * LOG2E_SCALE);
      float e3 = __builtin_amdgcn_exp2f(S[nt][3] * LOG2E_SCALE);
      const int base = (l4 * 4) * PST + nt * 16 + l15;
      p_wave[base] = e0; p_wave[base + PST] = e1;
      p_wave[base + 2 * PST] = e2; p_wave[base + 3 * PST] = e3;
      // f64 partial over this lane's 4 rows, then deterministic tree-reduce over l4 groups
      double csp = (double)e0 * (double)invL[0] + (double)e1 * (double)invL[1]
                 + (double)e2 * (double)invL[2] + (double)e3 * (double)invL[3];
      csp += __shfl_xor(csp, 16);
      csp += __shfl_xor(csp, 32);
      if (lane < 16) atomicAdd(&csrow[kc + nt * 16 + l15], csp);
    }
    // PV ks=0: A = P (LDS round-trip, per-wave private), B = vT batched fragments
    {
      const float* pp = p_wave + l15 * PST + l4 * 8;
      half8 pa = pack_h8_rtz(*(const float4*)pp, *(const float4*)(pp + 4));
#pragma unroll
      for (int dt = 0; dt < 8; ++dt)
        O[dt] = __builtin_amdgcn_mfma_f32_16x16x32_f16(pa, vb[dt], O[dt], 0, 0, 0);
    }
    // PV ks=1 (vb renames in SSA; loads can overlap ks=0 MFMAs)
#pragma unroll
    for (int dt = 0; dt < 8; ++dt)
      vb[dt] = *(const half8*)(vh + (size_t)(dt * 16 + l15) * NN + kc + 32 + l4 * 8);
    {
      const float* pp = p_wave + l15 * PST + 32 + l4 * 8;
      half8 pa = pack_h8_rtz(*(const float4*)pp, *(const float4*)(pp + 4));
#pragma unroll
      for (int dt = 0; dt < 8; ++dt)
        O[dt] = __builtin_amdgcn_mfma_f32_16x16x32_f16(pa, vb[dt], O[dt], 0, 0, 0);
    }
  }
#undef LOADK2
  // epilogue: normalize rows, store o
#pragma unroll
  for (int dt = 0; dt < 8; ++dt)
#pragma unroll
    for (int r = 0; r < 4; ++r) {
      size_t idx = ((size_t)(h * NN + rowbase + l4 * 4 + r)) * D + dt * 16 + l15;
      out[idx] = O[dt][r] * invL[r];
    }
}

// ---------------- exact top-k per (h,g) on f64 cs: mask |= top-896 ----------------
__global__ __launch_bounds__(256)
void topk_kernel(const double* __restrict__ csb, float* __restrict__ maskb) {
  const int hg = blockIdx.x;
  const double* cs = csb + (size_t)hg * NN;
  float* mask = maskb + (size_t)hg * NN;
  __shared__ unsigned long long vals[NN];  // 24 KB; cs > 0 so u64 order == double order
  __shared__ int wsum[4];
  const int tid = threadIdx.x;
  for (int i = tid; i < NN; i += 256)
    vals[i] = (unsigned long long)__double_as_longlong(cs[i]);
  __syncthreads();
  // greedy MSB search: largest T with count(v >= T) >= K  ->  T = K-th largest value
  unsigned long long T = 0ull;
  for (int b = 62; b >= 0; --b) {
    unsigned long long cand = T | (1ull << b);
    int c = 0;
    for (int i = tid; i < NN; i += 256) c += (vals[i] >= cand) ? 1 : 0;
#pragma unroll
    for (int off = 32; off; off >>= 1) c += __shfl_xor(c, off);
    if ((tid & 63) == 0) wsum[tid >> 6] = c;
    __syncthreads();
    int total = wsum[0] + wsum[1] + wsum[2] + wsum[3];
    if (total >= TOPK_K) T = cand;
    __syncthreads();
  }
  // lax.top_k tie-break: all (> T), then (== T) in increasing index order
  int c = 0;
  for (int i = tid; i < NN; i += 256) c += (vals[i] > T) ? 1 : 0;
#pragma unroll
  for (int off = 32; off; off >>= 1) c += __shfl_xor(c, off);
  if ((tid & 63) == 0) wsum[tid >> 6] = c;
  __syncthreads();
  int cgt = wsum[0] + wsum[1] + wsum[2] + wsum[3];
  int need = TOPK_K - cgt;
  for (int i = tid; i < NN; i += 256)
    if (vals[i] > T) mask[i] = 1.0f;
  __syncthreads();
  if (tid == 0) {
    int c2 = 0;
    for (int i = 0; i < NN && c2 < need; ++i)
      if (vals[i] == T) { mask[i] = 1.0f; ++c2; }
  }
}

// ---------------- sparse attention (single pass, plain f16) -> out2 = o - sp ----------------
__global__ __launch_bounds__(256, 3)
void sparse_kernel(const float* __restrict__ q, const _Float16* __restrict__ kf,
                   const _Float16* __restrict__ vT, const float* __restrict__ maskb,
                   float* __restrict__ out) {
  __shared__ float p_sh[4 * 16 * PST];
  const int tid = threadIdx.x;
  const int wave = tid >> 6, lane = tid & 63;
  const int l15 = lane & 15, l4 = lane >> 4;
  const int h = blockIdx.y;
  const int rowbase = blockIdx.x * 64 + wave * 16;
  const _Float16* kh = kf + (size_t)h * NN * D;
  const _Float16* vh = vT + (size_t)h * D * NN;
  float* p_wave = p_sh + wave * 16 * PST;

  half8 qa[4];
#pragma unroll
  for (int ds = 0; ds < 4; ++ds) {
    const float* qp = q + ((size_t)(h * NN + rowbase + l15)) * D + ds * 32 + l4 * 8;
    qa[ds] = pack_h8_rte(*(const float4*)qp, *(const float4*)(qp + 4));
  }

  const int gg0 = rowbase / BM;
  const float* mrow = maskb + ((size_t)h * G + gg0) * NN;

  half8 kb[2][4];
#define LOADK1(bb, t) { const size_t ko_ = (size_t)((t) * 16 + l15) * D + l4 * 8;        \
  _Pragma("unroll") for (int ds_ = 0; ds_ < 4; ++ds_)                                    \
    kb[bb][ds_] = *(const half8*)(kh + ko_ + ds_ * 32); }

  float lacc[4] = {0.f, 0.f, 0.f, 0.f};
  floatx4 O[8];
#pragma unroll
  for (int dt = 0; dt < 8; ++dt) O[dt] = fzero4();

  LOADK1(0, 0)
  for (int t4 = 0; t4 < 48; ++t4) {
    const int kc = t4 * 64;
    float mv[4];
#pragma unroll
    for (int nt = 0; nt < 4; ++nt) mv[nt] = mrow[kc + nt * 16 + l15];  // issue early
    floatx4 S[4];
#pragma unroll
    for (int nt = 0; nt < 4; ++nt) S[nt] = fzero4();
#pragma unroll
    for (int nt = 0; nt < 4; ++nt) {
      const int b = nt & 1;
      LOADK1(b ^ 1, t4 * 4 + nt + 1)
#pragma unroll
      for (int ds = 0; ds < 4; ++ds)
        S[nt] = __builtin_amdgcn_mfma_f32_16x16x32_f16(qa[ds], kb[b][ds], S[nt], 0, 0, 0);
    }
    half8 vb[8];
#pragma unroll
    for (int dt = 0; dt < 8; ++dt)
      vb[dt] = *(const half8*)(vh + (size_t)(dt * 16 + l15) * NN + kc + l4 * 8);
#pragma unroll
    for (int nt = 0; nt < 4; ++nt) {
      float e0 = __builtin_amdgcn_exp2f(S[nt][0] * LOG2E_SCALE) * mv[nt];
      float e1 = __builtin_amdgcn_exp2f(S[nt][1] * LOG2E_SCALE) * mv[nt];
      float e2 = __builtin_amdgcn_exp2f(S[nt][2] * LOG2E_SCALE) * mv[nt];
      float e3 = __builtin_amdgcn_exp2f(S[nt][3] * LOG2E_SCALE) * mv[nt];
      lacc[0] += e0; lacc[1] += e1; lacc[2] += e2; lacc[3] += e3;
      const int base = (l4 * 4) * PST + nt * 16 + l15;
      p_wave[base] = e0; p_wave[base + PST] = e1;
      p_wave[base + 2 * PST] = e2; p_wave[base + 3 * PST] = e3;
    }
    {
      const float* pp = p_wave + l15 * PST + l4 * 8;
      half8 pa = pack_h8_rtz(*(const float4*)pp, *(const float4*)(pp + 4));
#pragma unroll
      for (int dt = 0; dt < 8; ++dt)
        O[dt] = __builtin_amdgcn_mfma_f32_16x16x32_f16(pa, vb[dt], O[dt], 0, 0, 0);
    }
#pragma unroll
    for (int dt = 0; dt < 8; ++dt)
      vb[dt] = *(const half8*)(vh + (size_t)(dt * 16 + l15) * NN + kc + 32 + l4 * 8);
    {
      const float* pp = p_wave + l15 * PST + 32 + l4 * 8;
      half8 pa = pack_h8_rtz(*(const float4*)pp, *(const float4*)(pp + 4));
#pragma unroll
      for (int dt = 0; dt < 8; ++dt)
        O[dt] = __builtin_amdgcn_mfma_f32_16x16x32_f16(pa, vb[dt], O[dt], 0, 0, 0);
    }
  }
#undef LOADK1
  float invl[4];
#pragma unroll
  for (int r = 0; r < 4; ++r) {
    float x = lacc[r];
    x += __shfl_xor(x, 1); x += __shfl_xor(x, 2);
    x += __shfl_xor(x, 4); x += __shfl_xor(x, 8);
    invl[r] = 1.0f / x;
  }
#pragma unroll
  for (int dt = 0; dt < 8; ++dt)
#pragma unroll
    for (int r = 0; r < 4; ++r) {
      size_t idx = ((size_t)(h * NN + rowbase + l4 * 4 + r)) * D + dt * 16 + l15;
      out[OUT2_OFF + idx] = out[idx] - O[dt][r] * invl[r];
    }
}

// ---------------- launch ----------------
extern "C" void kernel_launch(void* const* d_in, const int* in_sizes, int n_in,
                              void* d_out, int out_size, void* d_ws, size_t ws_size,
                              hipStream_t stream) {
  const float* q = (const float*)d_in[0];
  const float* k = (const float*)d_in[1];
  const float* v = (const float*)d_in[2];
  float* out = (float*)d_out;
  char* wsb = (char*)d_ws;

  // ws layout: khi | klo | vT | cs(double) | mask   (~71 MB total)
  _Float16* khi = (_Float16*)wsb;
  _Float16* klo = (_Float16*)(wsb + KV_HALF_BYTES);
  _Float16* vT  = (_Float16*)(wsb + 2 * KV_HALF_BYTES);
  double* csb   = (double*)(wsb + 3 * KV_HALF_BYTES);
  float* maskb  = (float*)(wsb + 3 * KV_HALF_BYTES + CSD_BYTES);

  (void)hipMemsetAsync(csb, 0, CSD_BYTES, stream);
  cvt_k_kernel<<<dim3((H * NN * D) / (8 * 256)), dim3(256), 0, stream>>>(k, khi, klo);
  cvt_vT_kernel<<<dim3(NN / 64, D / 64, H), dim3(256), 0, stream>>>(v, vT);
  rmask_kernel<<<dim3(H * G * NN / 256), dim3(256), 0, stream>>>(maskb);
  dense_kernel<<<dim3(NN / 64, H), dim3(256), 0, stream>>>(q, khi, klo, vT, out, csb);
  topk_kernel<<<dim3(H * G), dim3(256), 0, stream>>>(csb, maskb);
  sparse_kernel<<<dim3(NN / 64, H), dim3(256), 0, stream>>>(q, khi, vT, maskb, out);
}

// Round 2
// 1278.069 us; speedup vs baseline: 3.0244x; 3.0244x over previous
//
#include <hip/hip_runtime.h>
#include <math.h>

// Problem constants (b=1 hard-coded)
#define H  24
#define NN 3072
#define D  128
#define G  16
#define BM 192
#define TOPK_K 896
#define PST 68             // P-tile LDS row stride (floats)
#define OUT2_OFF ((size_t)H * NN * D)
#define KV_HALF_BYTES ((size_t)H * NN * D * 2)   // 18874368
#define CSD_BYTES ((size_t)H * G * NN * 8)       // 9437184 (float64 cs)

// exp(s*scale) = exp2(s * scale * log2(e)); scale = 1/sqrt(128)
#define LOG2E_SCALE 0.12751743822f

typedef _Float16 half8 __attribute__((ext_vector_type(8)));
typedef _Float16 half4v __attribute__((ext_vector_type(4)));
typedef __fp16 fp16x2 __attribute__((ext_vector_type(2)));
typedef float floatx4 __attribute__((ext_vector_type(4)));

// async global->LDS, 16B per lane; LDS dest = wave-uniform base + lane*16 (HW rule)
#define GLOAD_LDS(g, l) __builtin_amdgcn_global_load_lds( \
    (const __attribute__((address_space(1))) void*)(g),   \
    (__attribute__((address_space(3))) void*)(l), 16, 0, 0)
#define WAITVM(N) asm volatile("s_waitcnt vmcnt(" #N ")" ::: "memory")

__device__ __forceinline__ floatx4 fzero4() {
  floatx4 z = {0.f, 0.f, 0.f, 0.f};
  return z;
}
// RTE pack (unbiased) — used for input fragments
__device__ __forceinline__ half8 pack_h8_rte(float4 a, float4 b) {
  half8 r;
  r[0] = (_Float16)a.x; r[1] = (_Float16)a.y; r[2] = (_Float16)a.z; r[3] = (_Float16)a.w;
  r[4] = (_Float16)b.x; r[5] = (_Float16)b.y; r[6] = (_Float16)b.z; r[7] = (_Float16)b.w;
  return r;
}
// RTZ packed cvt (1 instr per pair) — used for P (p>=0; small bias cancels in o - sp)
__device__ __forceinline__ half8 pack_h8_rtz(float4 a, float4 b) {
  fp16x2 h0 = __builtin_amdgcn_cvt_pkrtz(a.x, a.y);
  fp16x2 h1 = __builtin_amdgcn_cvt_pkrtz(a.z, a.w);
  fp16x2 h2 = __builtin_amdgcn_cvt_pkrtz(b.x, b.y);
  fp16x2 h3 = __builtin_amdgcn_cvt_pkrtz(b.z, b.w);
  half8 r;
  r[0] = (_Float16)h0[0]; r[1] = (_Float16)h0[1];
  r[2] = (_Float16)h1[0]; r[3] = (_Float16)h1[1];
  r[4] = (_Float16)h2[0]; r[5] = (_Float16)h2[1];
  r[6] = (_Float16)h3[0]; r[7] = (_Float16)h3[1];
  return r;
}
// residual: x - (float)f16(x)
__device__ __forceinline__ half8 pack_h8_residual(float4 a, float4 b, half8 hi) {
  float4 ra = make_float4(a.x - (float)hi[0], a.y - (float)hi[1],
                          a.z - (float)hi[2], a.w - (float)hi[3]);
  float4 rb = make_float4(b.x - (float)hi[4], b.y - (float)hi[5],
                          b.z - (float)hi[6], b.w - (float)hi[7]);
  return pack_h8_rte(ra, rb);
}

// ---------------- threefry2x32 (exact JAX semantics, validated round 1) ----------------
__device__ __forceinline__ void tf2x32(unsigned k0, unsigned k1, unsigned x0, unsigned x1,
                                       unsigned* o0, unsigned* o1) {
  unsigned ks2 = k0 ^ k1 ^ 0x1BD11BDAu;
  unsigned v0 = x0 + k0, v1 = x1 + k1;
#define TF_RND(r) { v0 += v1; v1 = (v1 << (r)) | (v1 >> (32 - (r))); v1 ^= v0; }
  TF_RND(13) TF_RND(15) TF_RND(26) TF_RND(6)   v0 += k1;  v1 += ks2 + 1u;
  TF_RND(17) TF_RND(29) TF_RND(16) TF_RND(24)  v0 += ks2; v1 += k0 + 2u;
  TF_RND(13) TF_RND(15) TF_RND(26) TF_RND(6)   v0 += k0;  v1 += k1 + 3u;
  TF_RND(17) TF_RND(29) TF_RND(16) TF_RND(24)  v0 += k1;  v1 += ks2 + 4u;
  TF_RND(13) TF_RND(15) TF_RND(26) TF_RND(6)   v0 += ks2; v1 += k0 + 5u;
#undef TF_RND
  *o0 = v0; *o1 = v1;
}

__global__ __launch_bounds__(256)
void rmask_kernel(float* __restrict__ mask) {
  const unsigned S = H * G * NN;
  unsigned i = blockIdx.x * 256u + threadIdx.x;
  if (i >= S) return;
  unsigned hb, lb, a, b;
  unsigned k1a, k1b, k2a, k2b;
  tf2x32(0u, 1u, 0u, 0u, &k1a, &k1b);
  tf2x32(0u, 1u, 0u, 1u, &k2a, &k2b);
  tf2x32(k1a, k1b, 0u, i, &a, &b); hb = a ^ b;
  tf2x32(k2a, k2b, 0u, i, &a, &b); lb = a ^ b;
  unsigned r = ((hb % 100u) * 96u + (lb % 100u)) % 100u;
  mask[i] = (r == 0u) ? 1.0f : 0.0f;
}

// ---------------- phase 0: k -> f16 hi + f16 residual (row-major) ----------------
__global__ __launch_bounds__(256)
void cvt_k_kernel(const float* __restrict__ k, _Float16* __restrict__ khi,
                  _Float16* __restrict__ klo) {
  size_t i = (size_t)blockIdx.x * 256 + threadIdx.x;   // 8 elems per thread
  const float4* src = (const float4*)k + i * 2;
  float4 a = src[0], b = src[1];
  half8 hi = pack_h8_rte(a, b);
  *(half8*)(khi + i * 8) = hi;
  *(half8*)(klo + i * 8) = pack_h8_residual(a, b, hi);
}

// ---------------- phase 0: v -> f16 transposed vT[h][d][key] ----------------
__global__ __launch_bounds__(256)
void cvt_vT_kernel(const float* __restrict__ v, _Float16* __restrict__ vT) {
  __shared__ _Float16 t[64][68];
  const int h = blockIdx.z, k0 = blockIdx.x * 64, d0 = blockIdx.y * 64;
  const int tid = threadIdx.x;
  const int c4 = tid & 15, r = tid >> 4;
#pragma unroll
  for (int i = 0; i < 4; ++i) {
    int row = r + i * 16;  // key row within tile
    float4 x = *(const float4*)(v + ((size_t)(h * NN + k0 + row)) * D + d0 + c4 * 4);
    t[c4 * 4 + 0][row] = (_Float16)x.x;
    t[c4 * 4 + 1][row] = (_Float16)x.y;
    t[c4 * 4 + 2][row] = (_Float16)x.z;
    t[c4 * 4 + 3][row] = (_Float16)x.w;
  }
  __syncthreads();
#pragma unroll
  for (int i = 0; i < 4; ++i) {
    int drow = r + i * 16;  // d within tile
    half4v val = *(const half4v*)&t[drow][c4 * 4];
    *(half4v*)(vT + (size_t)(h * D + d0 + drow) * NN + k0 + c4 * 4) = val;
  }
}

// ---------------- dense attention: LDS-staged double-buffered pipeline ----------------
// 8 waves x 16 query rows = 128 rows/block; K tile = 64 keys.
// Per tile: khi(16KB)+klo(16KB)+vT(16KB) staged via global_load_lds (async, counted
// vmcnt(N), never 0 in the loop), double-buffered; 2 raw s_barriers per tile.
// Bank-conflict fix (T2 via m173): LDS stays LINEAR (global_load_lds requirement);
// the global SOURCE column group is pre-swizzled gc = pc ^ (row&7), and fragment
// ds_reads apply the same XOR. XCD-aware block swizzle (576 = 8*72) for K L2 reuse.
__global__ __launch_bounds__(512, 2)
void dense_kernel(const float* __restrict__ q, const _Float16* __restrict__ khi_g,
                  const _Float16* __restrict__ klo_g, const _Float16* __restrict__ vT,
                  float* __restrict__ out, double* __restrict__ csb) {
  __shared__ __align__(16) _Float16 sk[2][3 * 8192];   // [khi | klo | v] per buffer, 96 KB
  __shared__ __align__(16) float p_sh[8 * 16 * PST];   // per-wave private P stripes, 34 KB
  const int tid = threadIdx.x;
  const int wave = tid >> 6, lane = tid & 63;
  const int l15 = lane & 15, l4 = lane >> 4;
  // XCD swizzle: consecutive dispatch ids round-robin XCDs; give each XCD a
  // contiguous chunk of (head-major) work. 576 = 8 * 72, bijective.
  const int wq = ((blockIdx.x & 7) * 72) + (blockIdx.x >> 3);
  const int h = wq / 24;
  const int m0 = (wq % 24) * 128;
  const int rowbase = m0 + wave * 16;
  const _Float16* khi = khi_g + (size_t)h * NN * D;
  const _Float16* klo = klo_g + (size_t)h * NN * D;
  const _Float16* vh = vT + (size_t)h * D * NN;
  float* p_wave = p_sh + wave * 16 * PST;

  // staging geometry (K): chunk c = wave*4+i; region = (c<16)?khi:klo; cr = c&15
  // row = cr*4 + l4, physical col16 = l15, source col16 = l15 ^ (row&7)
  const _Float16* ksrc = (wave < 4) ? khi : klo;
  const int kreg0 = (wave < 4) ? 0 : 8192;
  const int krow0 = (wave & 3) * 16 + l4;
  const int vgc = (lane & 7) ^ (lane >> 3);   // V source swizzle (row&7 == lane>>3)

#define STAGE_K(kc_, buf_) {                                                     \
  _Pragma("unroll") for (int i_ = 0; i_ < 4; ++i_) {                             \
    int row_ = krow0 + i_ * 4;                                                   \
    int gc_ = l15 ^ (l4 + 4 * (i_ & 1));                                         \
    GLOAD_LDS(ksrc + (size_t)((kc_) + row_) * D + gc_ * 8,                       \
              &sk[buf_][kreg0 + ((wave & 3) * 4 + i_) * 512]);                   \
  } }
#define STAGE_V(kc_, buf_) {                                                     \
  _Pragma("unroll") for (int i_ = 0; i_ < 2; ++i_) {                             \
    int vr_ = (wave * 2 + i_) * 8 + (lane >> 3);                                 \
    GLOAD_LDS(vh + (size_t)vr_ * NN + (kc_) + vgc * 8,                           \
              &sk[buf_][16384 + (wave * 2 + i_) * 512]);                         \
  } }

  // fragment read columns (same XOR as the staged source swizzle)
  const int kxor = l15 & 7;
  int kcol[4], vcol[2];
#pragma unroll
  for (int ds = 0; ds < 4; ++ds) kcol[ds] = ((ds * 4 + l4) ^ kxor) * 8;
#pragma unroll
  for (int ks = 0; ks < 2; ++ks) vcol[ks] = ((ks * 4 + l4) ^ kxor) * 8;

  // Q A-fragments hi+lo, register-resident: A[m=l15][k=l4*8+j]
  half8 qh[4], ql[4];
#pragma unroll
  for (int ds = 0; ds < 4; ++ds) {
    const float* qp = q + ((size_t)(h * NN + rowbase + l15)) * D + ds * 32 + l4 * 8;
    float4 a = *(const float4*)qp, b = *(const float4*)(qp + 4);
    qh[ds] = pack_h8_rte(a, b);
    ql[ds] = pack_h8_residual(a, b, qh[ds]);
  }

  // ---- pass 1: row sums L (split-precision QK^T), K-only staging ----
  float Lacc[4] = {0.f, 0.f, 0.f, 0.f};
  int cur = 0;
  STAGE_K(0, 0)
#pragma unroll 1
  for (int t = 0; t < 48; ++t) {
    const int tn = (t + 1 < 48) ? (t + 1) * 64 : 0;
    STAGE_K(tn, cur ^ 1)
    WAITVM(4);
    __builtin_amdgcn_s_barrier();
    const _Float16* bk = sk[cur];
    floatx4 S[4];
#pragma unroll
    for (int nt = 0; nt < 4; ++nt) S[nt] = fzero4();
#pragma unroll
    for (int nt = 0; nt < 4; ++nt) {
      const int rb = (nt * 16 + l15) * 128;
#pragma unroll
      for (int ds = 0; ds < 4; ++ds) {
        half8 kbh = *(const half8*)&bk[rb + kcol[ds]];
        half8 kbl = *(const half8*)&bk[8192 + rb + kcol[ds]];
        S[nt] = __builtin_amdgcn_mfma_f32_16x16x32_f16(qh[ds], kbh, S[nt], 0, 0, 0);
        S[nt] = __builtin_amdgcn_mfma_f32_16x16x32_f16(qh[ds], kbl, S[nt], 0, 0, 0);
        S[nt] = __builtin_amdgcn_mfma_f32_16x16x32_f16(ql[ds], kbh, S[nt], 0, 0, 0);
      }
    }
#pragma unroll
    for (int nt = 0; nt < 4; ++nt)
#pragma unroll
      for (int r = 0; r < 4; ++r)
        Lacc[r] += __builtin_amdgcn_exp2f(S[nt][r] * LOG2E_SCALE);
    __builtin_amdgcn_s_barrier();
    cur ^= 1;
  }
  float invL[4];
#pragma unroll
  for (int r = 0; r < 4; ++r) {
    float x = Lacc[r];
    x += __shfl_xor(x, 1); x += __shfl_xor(x, 2);
    x += __shfl_xor(x, 4); x += __shfl_xor(x, 8);
    invL[r] = 1.0f / x;   // row = l4*4 + r (matches C-layout)
  }

  // ---- pass 2: p, cs (f64, wave-reduced atomics), PV ----
  // After pass 1, cur==0 and tile 0's K is already staged (by iteration t=47);
  // stage only its V here. Outstanding counts line up: vmcnt(6) in iter 0 waits
  // for tile0's 4 K + 2 V loads.
  const int gg0 = rowbase / BM;
  double* csrow = csb + ((size_t)h * G + gg0) * NN;
  floatx4 O[8];
#pragma unroll
  for (int dt = 0; dt < 8; ++dt) O[dt] = fzero4();
  STAGE_V(0, 0)
#pragma unroll 1
  for (int t = 0; t < 48; ++t) {
    const int kc = t * 64;
    const int tn = (t + 1 < 48) ? (t + 1) * 64 : 0;
    STAGE_K(tn, cur ^ 1)
    STAGE_V(tn, cur ^ 1)
    WAITVM(6);
    __builtin_amdgcn_s_barrier();
    const _Float16* bk = sk[cur];
    const _Float16* bv = sk[cur] + 16384;
    floatx4 S[4];
#pragma unroll
    for (int nt = 0; nt < 4; ++nt) S[nt] = fzero4();
#pragma unroll
    for (int nt = 0; nt < 4; ++nt) {
      const int rb = (nt * 16 + l15) * 128;
#pragma unroll
      for (int ds = 0; ds < 4; ++ds) {
        half8 kbh = *(const half8*)&bk[rb + kcol[ds]];
        half8 kbl = *(const half8*)&bk[8192 + rb + kcol[ds]];
        S[nt] = __builtin_amdgcn_mfma_f32_16x16x32_f16(qh[ds], kbh, S[nt], 0, 0, 0);
        S[nt] = __builtin_amdgcn_mfma_f32_16x16x32_f16(qh[ds], kbl, S[nt], 0, 0, 0);
        S[nt] = __builtin_amdgcn_mfma_f32_16x16x32_f16(ql[ds], kbh, S[nt], 0, 0, 0);
      }
    }
    // exp, cs partial (f64), LDS P stripe
#pragma unroll
    for (int nt = 0; nt < 4; ++nt) {
      float e0 = __builtin_amdgcn_exp2f(S[nt][0] * LOG2E_SCALE);
      float e1 = __builtin_amdgcn_exp2f(S[nt][1] * LOG2E_SCALE);
      float e2 = __builtin_amdgcn_exp2f(S[nt][2] * LOG2E_SCALE);
      float e3 = __builtin_amdgcn_exp2f(S[nt][3] * LOG2E_SCALE);
      const int base = (l4 * 4) * PST + nt * 16 + l15;
      p_wave[base] = e0; p_wave[base + PST] = e1;
      p_wave[base + 2 * PST] = e2; p_wave[base + 3 * PST] = e3;
      double csp = (double)e0 * (double)invL[0] + (double)e1 * (double)invL[1]
                 + (double)e2 * (double)invL[2] + (double)e3 * (double)invL[3];
      csp += __shfl_xor(csp, 16);
      csp += __shfl_xor(csp, 32);
      if (lane < 16) atomicAdd(&csrow[kc + nt * 16 + l15], csp);
    }
    // PV: A = P (per-wave LDS round-trip), B = staged vT fragments
#pragma unroll
    for (int ks = 0; ks < 2; ++ks) {
      const float* pp = p_wave + l15 * PST + ks * 32 + l4 * 8;
      half8 pa = pack_h8_rtz(*(const float4*)pp, *(const float4*)(pp + 4));
#pragma unroll
      for (int dt = 0; dt < 8; ++dt) {
        half8 vb = *(const half8*)&bv[(dt * 16 + l15) * 64 + vcol[ks]];
        O[dt] = __builtin_amdgcn_mfma_f32_16x16x32_f16(pa, vb, O[dt], 0, 0, 0);
      }
    }
    __builtin_amdgcn_s_barrier();
    cur ^= 1;
  }
#undef STAGE_K
#undef STAGE_V
  // epilogue: normalize rows, store o
#pragma unroll
  for (int dt = 0; dt < 8; ++dt)
#pragma unroll
    for (int r = 0; r < 4; ++r) {
      size_t idx = ((size_t)(h * NN + rowbase + l4 * 4 + r)) * D + dt * 16 + l15;
      out[idx] = O[dt][r] * invL[r];
    }
}

// ---------------- exact top-k per (h,g) on f64 cs: mask |= top-896 ----------------
__global__ __launch_bounds__(256)
void topk_kernel(const double* __restrict__ csb, float* __restrict__ maskb) {
  const int hg = blockIdx.x;
  const double* cs = csb + (size_t)hg * NN;
  float* mask = maskb + (size_t)hg * NN;
  __shared__ unsigned long long vals[NN];  // 24 KB; cs > 0 so u64 order == double order
  __shared__ int wsum[4];
  const int tid = threadIdx.x;
  for (int i = tid; i < NN; i += 256)
    vals[i] = (unsigned long long)__double_as_longlong(cs[i]);
  __syncthreads();
  // greedy MSB search: largest T with count(v >= T) >= K  ->  T = K-th largest value
  unsigned long long T = 0ull;
  for (int b = 62; b >= 0; --b) {
    unsigned long long cand = T | (1ull << b);
    int c = 0;
    for (int i = tid; i < NN; i += 256) c += (vals[i] >= cand) ? 1 : 0;
#pragma unroll
    for (int off = 32; off; off >>= 1) c += __shfl_xor(c, off);
    if ((tid & 63) == 0) wsum[tid >> 6] = c;
    __syncthreads();
    int total = wsum[0] + wsum[1] + wsum[2] + wsum[3];
    if (total >= TOPK_K) T = cand;
    __syncthreads();
  }
  // lax.top_k tie-break: all (> T), then (== T) in increasing index order
  int c = 0;
  for (int i = tid; i < NN; i += 256) c += (vals[i] > T) ? 1 : 0;
#pragma unroll
  for (int off = 32; off; off >>= 1) c += __shfl_xor(c, off);
  if ((tid & 63) == 0) wsum[tid >> 6] = c;
  __syncthreads();
  int cgt = wsum[0] + wsum[1] + wsum[2] + wsum[3];
  int need = TOPK_K - cgt;
  for (int i = tid; i < NN; i += 256)
    if (vals[i] > T) mask[i] = 1.0f;
  __syncthreads();
  if (tid == 0) {
    int c2 = 0;
    for (int i = 0; i < NN && c2 < need; ++i)
      if (vals[i] == T) { mask[i] = 1.0f; ++c2; }
  }
}

// ---------------- sparse attention (single pass, plain f16) -> out2 = o - sp ----------------
// Same LDS-staged pipeline as dense_kernel, single pass, no residual split.
__global__ __launch_bounds__(512, 2)
void sparse_kernel(const float* __restrict__ q, const _Float16* __restrict__ kf,
                   const _Float16* __restrict__ vT, const float* __restrict__ maskb,
                   float* __restrict__ out) {
  __shared__ __align__(16) _Float16 sk[2][2 * 8192];   // [kf | v] per buffer, 64 KB
  __shared__ __align__(16) float p_sh[8 * 16 * PST];
  const int tid = threadIdx.x;
  const int wave = tid >> 6, lane = tid & 63;
  const int l15 = lane & 15, l4 = lane >> 4;
  const int wq = ((blockIdx.x & 7) * 72) + (blockIdx.x >> 3);
  const int h = wq / 24;
  const int m0 = (wq % 24) * 128;
  const int rowbase = m0 + wave * 16;
  const _Float16* kh = kf + (size_t)h * NN * D;
  const _Float16* vh = vT + (size_t)h * D * NN;
  float* p_wave = p_sh + wave * 16 * PST;

  const int vgc = (lane & 7) ^ (lane >> 3);
#define SSTAGE(kc_, buf_) {                                                      \
  _Pragma("unroll") for (int i_ = 0; i_ < 2; ++i_) {                             \
    int row_ = (wave * 2 + i_) * 4 + l4;                                         \
    int gc_ = l15 ^ (l4 + 4 * (i_ & 1));                                         \
    GLOAD_LDS(kh + (size_t)((kc_) + row_) * D + gc_ * 8,                         \
              &sk[buf_][(wave * 2 + i_) * 512]);                                 \
  }                                                                              \
  _Pragma("unroll") for (int i_ = 0; i_ < 2; ++i_) {                             \
    int vr_ = (wave * 2 + i_) * 8 + (lane >> 3);                                 \
    GLOAD_LDS(vh + (size_t)vr_ * NN + (kc_) + vgc * 8,                           \
              &sk[buf_][8192 + (wave * 2 + i_) * 512]);                          \
  } }

  const int kxor = l15 & 7;
  int kcol[4], vcol[2];
#pragma unroll
  for (int ds = 0; ds < 4; ++ds) kcol[ds] = ((ds * 4 + l4) ^ kxor) * 8;
#pragma unroll
  for (int ks = 0; ks < 2; ++ks) vcol[ks] = ((ks * 4 + l4) ^ kxor) * 8;

  half8 qa[4];
#pragma unroll
  for (int ds = 0; ds < 4; ++ds) {
    const float* qp = q + ((size_t)(h * NN + rowbase + l15)) * D + ds * 32 + l4 * 8;
    qa[ds] = pack_h8_rte(*(const float4*)qp, *(const float4*)(qp + 4));
  }

  const int gg0 = rowbase / BM;
  const float* mrow = maskb + ((size_t)h * G + gg0) * NN;

  float lacc[4] = {0.f, 0.f, 0.f, 0.f};
  floatx4 O[8];
#pragma unroll
  for (int dt = 0; dt < 8; ++dt) O[dt] = fzero4();

  int cur = 0;
  SSTAGE(0, 0)
#pragma unroll 1
  for (int t = 0; t < 48; ++t) {
    const int kc = t * 64;
    const int tn = (t + 1 < 48) ? (t + 1) * 64 : 0;
    SSTAGE(tn, cur ^ 1)
    WAITVM(4);
    __builtin_amdgcn_s_barrier();
    const _Float16* bk = sk[cur];
    const _Float16* bv = sk[cur] + 8192;
    float mv[4];
#pragma unroll
    for (int nt = 0; nt < 4; ++nt) mv[nt] = mrow[kc + nt * 16 + l15];  // issue early
    floatx4 S[4];
#pragma unroll
    for (int nt = 0; nt < 4; ++nt) S[nt] = fzero4();
#pragma unroll
    for (int nt = 0; nt < 4; ++nt) {
      const int rb = (nt * 16 + l15) * 128;
#pragma unroll
      for (int ds = 0; ds < 4; ++ds) {
        half8 kb = *(const half8*)&bk[rb + kcol[ds]];
        S[nt] = __builtin_amdgcn_mfma_f32_16x16x32_f16(qa[ds], kb, S[nt], 0, 0, 0);
      }
    }
#pragma unroll
    for (int nt = 0; nt < 4; ++nt) {
      float e0 = __builtin_amdgcn_exp2f(S[nt][0] * LOG2E_SCALE) * mv[nt];
      float e1 = __builtin_amdgcn_exp2f(S[nt][1] * LOG2E_SCALE) * mv[nt];
      float e2 = __builtin_amdgcn_exp2f(S[nt][2] * LOG2E_SCALE) * mv[nt];
      float e3 = __builtin_amdgcn_exp2f(S[nt][3] * LOG2E_SCALE) * mv[nt];
      lacc[0] += e0; lacc[1] += e1; lacc[2] += e2; lacc[3] += e3;
      const int base = (l4 * 4) * PST + nt * 16 + l15;
      p_wave[base] = e0; p_wave[base + PST] = e1;
      p_wave[base + 2 * PST] = e2; p_wave[base + 3 * PST] = e3;
    }
#pragma unroll
    for (int ks = 0; ks < 2; ++ks) {
      const float* pp = p_wave + l15 * PST + ks * 32 + l4 * 8;
      half8 pa = pack_h8_rtz(*(const float4*)pp, *(const float4*)(pp + 4));
#pragma unroll
      for (int dt = 0; dt < 8; ++dt) {
        half8 vb = *(const half8*)&bv[(dt * 16 + l15) * 64 + vcol[ks]];
        O[dt] = __builtin_amdgcn_mfma_f32_16x16x32_f16(pa, vb, O[dt], 0, 0, 0);
      }
    }
    __builtin_amdgcn_s_barrier();
    cur ^= 1;
  }
#undef SSTAGE
  float invl[4];
#pragma unroll
  for (int r = 0; r < 4; ++r) {
    float x = lacc[r];
    x += __shfl_xor(x, 1); x += __shfl_xor(x, 2);
    x += __shfl_xor(x, 4); x += __shfl_xor(x, 8);
    invl[r] = 1.0f / x;
  }
#pragma unroll
  for (int dt = 0; dt < 8; ++dt)
#pragma unroll
    for (int r = 0; r < 4; ++r) {
      size_t idx = ((size_t)(h * NN + rowbase + l4 * 4 + r)) * D + dt * 16 + l15;
      out[OUT2_OFF + idx] = out[idx] - O[dt][r] * invl[r];
    }
}

// ---------------- launch ----------------
extern "C" void kernel_launch(void* const* d_in, const int* in_sizes, int n_in,
                              void* d_out, int out_size, void* d_ws, size_t ws_size,
                              hipStream_t stream) {
  const float* q = (const float*)d_in[0];
  const float* k = (const float*)d_in[1];
  const float* v = (const float*)d_in[2];
  float* out = (float*)d_out;
  char* wsb = (char*)d_ws;

  // ws layout: khi | klo | vT | cs(double) | mask   (~71 MB total)
  _Float16* khi = (_Float16*)wsb;
  _Float16* klo = (_Float16*)(wsb + KV_HALF_BYTES);
  _Float16* vT  = (_Float16*)(wsb + 2 * KV_HALF_BYTES);
  double* csb   = (double*)(wsb + 3 * KV_HALF_BYTES);
  float* maskb  = (float*)(wsb + 3 * KV_HALF_BYTES + CSD_BYTES);

  (void)hipMemsetAsync(csb, 0, CSD_BYTES, stream);
  cvt_k_kernel<<<dim3((H * NN * D) / (8 * 256)), dim3(256), 0, stream>>>(k, khi, klo);
  cvt_vT_kernel<<<dim3(NN / 64, D / 64, H), dim3(256), 0, stream>>>(v, vT);
  rmask_kernel<<<dim3(H * G * NN / 256), dim3(256), 0, stream>>>(maskb);
  dense_kernel<<<dim3((NN / 128) * H), dim3(512), 0, stream>>>(q, khi, klo, vT, out, csb);
  topk_kernel<<<dim3(H * G), dim3(256), 0, stream>>>(csb, maskb);
  sparse_kernel<<<dim3((NN / 128) * H), dim3(512), 0, stream>>>(q, khi, vT, maskb, out);
}